// Round 7
// baseline (203.443 us; speedup 1.0000x reference)
//
#include <hip/hip_runtime.h>
#include <math.h>

#define N_TOK 4096
#define DIM 256
#define NHEAD 4
#define DPH 64
#define NEXP 9
#define SCALE 0.25f
#define MAXST 80    // 64-row supertiles: <= 64 + 9
#define GPAD 4736   // 64-aligned grouped rows upper bound
#define VPITCH 4736
#define NSPLIT 2    // key-range splits per (supertile, head)
// exp(x*SCALE) = 2^(x * SCALE*log2(e))
#define EXP2SCALE 0.36067376022224085f

typedef short s8 __attribute__((ext_vector_type(8)));
typedef short s4 __attribute__((ext_vector_type(4)));
typedef float f4 __attribute__((ext_vector_type(4)));

// HW packed f32->bf16 (RNE), 1 VALU op for 2 values (no builtin on gfx950).
static __device__ __forceinline__ unsigned cvt_pk_bf16(float a, float b) {
  unsigned r;
  asm("v_cvt_pk_bf16_f32 %0, %1, %2" : "=v"(r) : "v"(a), "v"(b));
  return r;
}

static __device__ __forceinline__ float exp2_hw(float x) {
  float r;
  asm("v_exp_f32 %0, %1" : "=v"(r) : "v"(x));
  return r;
}

static __device__ __forceinline__ float wave_sum(float v) {
#pragma unroll
  for (int o = 32; o > 0; o >>= 1) v += __shfl_xor(v, o, 64);
  return v;
}

// Agent-scope (sc1) relaxed store: performed at the MALL, the cross-XCD
// coherence point -> peer XCDs can read it after an acquire-inv WITHOUT the
// writer doing a full L2 writeback (buffer_wbl2). This is the flush-free
// producer side of the last-finisher merge.
static __device__ __forceinline__ void store_agent(float* p, float v) {
  __hip_atomic_store(p, v, __ATOMIC_RELAXED, __HIP_MEMORY_SCOPE_AGENT);
}

// ---------------------------------------------------------------------------
// Kernel 1: prep. Block 0: bucket tokens (atomic-free ballot histogram +
// deterministic rank scatter) + zero the per-supertile finish counters.
// Blocks 1..448: W fp32 [d][h] -> WbT bf16 [slab][h][d]. Blocks 449..512:
// x -> bf16 cast.
// ---------------------------------------------------------------------------
__global__ __launch_bounds__(256) void k_prep(
    const float* __restrict__ x, const int* __restrict__ label,
    const float* __restrict__ Wq, const float* __restrict__ Wk,
    const float* __restrict__ Wv, const float* __restrict__ Wf,
    int* __restrict__ perm, int* __restrict__ iperm, int* __restrict__ gs,
    int* __restrict__ gep, int* __restrict__ st_e, int* __restrict__ st_row,
    int* __restrict__ nstp, int* __restrict__ cnt, short* __restrict__ WbT,
    short* __restrict__ xb) {
  int b = blockIdx.x;
  int tid = threadIdx.x;
  if (b == 0) {
    __shared__ int cnt_s[4][NEXP];  // per-wave counts
    __shared__ int gsh[NEXP];       // group starts (LDS copy)
    if (tid < MAXST) cnt[tid] = 0;  // finish counters for k_attn's merge
    int wl = tid >> 6, lane = tid & 63;
    int lab[16];
#pragma unroll
    for (int i = 0; i < 16; i++) lab[i] = label[wl * 1024 + i * 64 + lane];

    int cw[NEXP];
#pragma unroll
    for (int e = 0; e < NEXP; e++) cw[e] = 0;
#pragma unroll
    for (int i = 0; i < 16; i++)
#pragma unroll
      for (int e = 0; e < NEXP; e++)
        cw[e] += __popcll(__ballot(lab[i] == e));
    if (lane == 0)
#pragma unroll
      for (int e = 0; e < NEXP; e++) cnt_s[wl][e] = cw[e];
    __syncthreads();

    if (tid == 0) {
      int run = 0, ns = 0;
      for (int e = 0; e < NEXP; e++) {
        int tot = cnt_s[0][e] + cnt_s[1][e] + cnt_s[2][e] + cnt_s[3][e];
        gs[e] = run;
        gsh[e] = run;
        int end = run + tot;
        gep[e] = end;
        for (int r = run; r < end; r += 64) {
          st_e[ns] = e;
          st_row[ns] = r;
          ns++;
        }
        run = (end + 63) & ~63;  // 64-align next group start
      }
      *nstp = ns;
    }
    __syncthreads();

    int baseW[NEXP];
#pragma unroll
    for (int e = 0; e < NEXP; e++) {
      int bse = gsh[e];
      for (int w = 0; w < 4; w++)
        if (w < wl) bse += cnt_s[w][e];
      baseW[e] = bse;
    }
    int run2[NEXP];
#pragma unroll
    for (int e = 0; e < NEXP; e++) run2[e] = 0;
#pragma unroll
    for (int i = 0; i < 16; i++) {
      int t = wl * 1024 + i * 64 + lane;
      int lv = lab[i];
      unsigned long long below = (1ull << lane) - 1ull;
      int pos = 0;
#pragma unroll
      for (int e = 0; e < NEXP; e++) {
        unsigned long long mk = __ballot(lv == e);
        if (lv == e) pos = baseW[e] + run2[e] + __popcll(mk & below);
        run2[e] += __popcll(mk);
      }
      perm[pos] = t;
      iperm[t] = pos;
    }
  } else if (b <= 448) {
    // Weight transpose: slabs 0-8 Wq, 9-17 Wk, 18-26 Wv, 27 Wf; 16 tiles/slab.
    __shared__ short tile[64 * 68];
    int vt = b - 1;
    int slab = vt >> 4;
    const float* src = (slab < 9)    ? Wq + (size_t)slab * 65536
                       : (slab < 18) ? Wk + (size_t)(slab - 9) * 65536
                       : (slab < 27) ? Wv + (size_t)(slab - 18) * 65536
                                     : Wf;
    int xy = vt & 15;
    int d0 = (xy >> 2) * 64, h0 = (xy & 3) * 64;
    int rl = tid >> 4;
    int hh = (tid & 15) * 4;
#pragma unroll
    for (int p = 0; p < 4; p++) {
      int dl = p * 16 + rl;
      float4 v = *(const float4*)(src + (size_t)(d0 + dl) * 256 + h0 + hh);
      union { s4 v; unsigned u[2]; } o;
      o.u[0] = cvt_pk_bf16(v.x, v.y);
      o.u[1] = cvt_pk_bf16(v.z, v.w);
      *(s4*)&tile[dl * 68 + hh] = o.v;
    }
    __syncthreads();
    int h = tid >> 2, dq = (tid & 3) * 16;
    s8 pa, pb;
#pragma unroll
    for (int i = 0; i < 8; i++) {
      pa[i] = tile[(dq + i) * 68 + h];
      pb[i] = tile[(dq + 8 + i) * 68 + h];
    }
    short* dst = WbT + (size_t)slab * 65536 + (size_t)(h0 + h) * 256 + d0 + dq;
    *(s8*)dst = pa;
    *(s8*)(dst + 8) = pb;
  } else {
    // x -> bf16, token order.
    int tok = (b - 449) * 64 + (tid >> 2);
    int qd = (tid & 3) * 64;
    const float* src = x + (size_t)tok * DIM + qd;
    short* dst = xb + (size_t)tok * DIM + qd;
#pragma unroll
    for (int i = 0; i < 16; i++) {
      float4 v = *(const float4*)(src + i * 4);
      union { s4 v; unsigned u[2]; } o;
      o.u[0] = cvt_pk_bf16(v.x, v.y);
      o.u[1] = cvt_pk_bf16(v.z, v.w);
      *(s4*)(dst + i * 4) = o.v;
    }
  }
}

// ---------------------------------------------------------------------------
// Kernel 2: MFMA QKV projection (unchanged from the verified baseline).
// ---------------------------------------------------------------------------
__global__ __launch_bounds__(256) void k_proj(
    const short* __restrict__ xb, const short* __restrict__ WbT,
    const float* __restrict__ bq, const float* __restrict__ bk,
    const float* __restrict__ bv, const int* __restrict__ perm,
    const int* __restrict__ gep, const int* __restrict__ st_e,
    const int* __restrict__ st_row, const int* __restrict__ nstp,
    short* __restrict__ qg, short* __restrict__ kg, short* __restrict__ vgT) {
  int b = blockIdx.x;
  if (b >= *nstp) return;
  int gy = blockIdx.y;
  int mtx = blockIdx.z;
  int e = st_e[b];
  int row0 = st_row[b];
  int g1 = gep[e];
  int tid = threadIdx.x, wl = tid >> 6, lane = tid & 63;
  int m = lane & 15, quad = lane >> 4;

  __shared__ short st_s[4][16 * 72];  // per-wave store-transpose buffer

  int row = row0 + wl * 16 + m;
  int pr = perm[(row < g1) ? row : row0];  // clamp padding rows
  const short* Ap = xb + (size_t)pr * DIM + quad * 8;
  const short* Bp = WbT + (size_t)(mtx * 9 + e) * 65536 +
                    (size_t)(gy * 64 + m) * 256 + quad * 8;
  const float* bias = (mtx == 0) ? bq : (mtx == 1) ? bk : bv;

  s8 ac = *(const s8*)Ap;
  s8 bc[4];
#pragma unroll
  for (int t = 0; t < 4; t++) bc[t] = *(const s8*)(Bp + t * 16 * 256);
  f4 acc[4];
#pragma unroll
  for (int t = 0; t < 4; t++) acc[t] = (f4){0.f, 0.f, 0.f, 0.f};
#pragma unroll
  for (int kc = 0; kc < 8; kc++) {
    s8 an = ac;
    s8 bn[4] = {bc[0], bc[1], bc[2], bc[3]};
    if (kc < 7) {
      an = *(const s8*)(Ap + (kc + 1) * 32);
#pragma unroll
      for (int t = 0; t < 4; t++)
        bn[t] = *(const s8*)(Bp + t * 16 * 256 + (kc + 1) * 32);
    }
#pragma unroll
    for (int t = 0; t < 4; t++)
      acc[t] = __builtin_amdgcn_mfma_f32_16x16x32_bf16(ac, bc[t], acc[t], 0, 0, 0);
    ac = an;
#pragma unroll
    for (int t = 0; t < 4; t++) bc[t] = bn[t];
  }

  if (mtx == 2) {
    // vgT[col][grow]: quad owns 4 consecutive grows per col -> 8B s4 stores.
#pragma unroll
    for (int t = 0; t < 4; t++) {
      int col = gy * 64 + t * 16 + m;
      float bs = bias[e * DIM + col];
      union { s4 v; unsigned u[2]; } o;
      o.u[0] = cvt_pk_bf16(acc[t][0] + bs, acc[t][1] + bs);
      o.u[1] = cvt_pk_bf16(acc[t][2] + bs, acc[t][3] + bs);
      *(s4*)&vgT[(size_t)col * VPITCH + row0 + wl * 16 + quad * 4] = o.v;
    }
  } else {
    // LDS transpose: C-layout -> [row][col] bf16, then coalesced stores.
    short* ws = st_s[wl];
#pragma unroll
    for (int t = 0; t < 4; t++) {
      int col = gy * 64 + t * 16 + m;
      float bs = bias[e * DIM + col];
      unsigned p01 = cvt_pk_bf16(acc[t][0] + bs, acc[t][1] + bs);
      unsigned p23 = cvt_pk_bf16(acc[t][2] + bs, acc[t][3] + bs);
      int base = quad * 4;
      ws[(base + 0) * 72 + t * 16 + m] = (short)p01;
      ws[(base + 1) * 72 + t * 16 + m] = (short)(p01 >> 16);
      ws[(base + 2) * 72 + t * 16 + m] = (short)p23;
      ws[(base + 3) * 72 + t * 16 + m] = (short)(p23 >> 16);
    }
    int rr = lane >> 2, cg2 = (lane & 3) * 16;
    s8 v0 = *(s8*)&ws[rr * 72 + cg2];
    s8 v1 = *(s8*)&ws[rr * 72 + cg2 + 8];
    short* dst = ((mtx == 1) ? kg : qg) +
                 (size_t)(row0 + wl * 16 + rr) * DIM + gy * 64 + cg2;
    *(s8*)dst = v0;
    *(s8*)(dst + 8) = v1;
  }
}

// ---------------------------------------------------------------------------
// Kernel 3: split-K MFMA flash attention + LAST-FINISHER out-proj/LN merge.
// Each (supertile, head, split) block writes agent-scope (sc1, MALL-visible)
// partials, then bumps cnt[supertile]. The 8th finisher acquires (inv) and
// performs the Wf GEMM + residual + LayerNorm for the supertile's 64 rows,
// overlapped with other blocks' attention tails. k_out kernel is gone.
// ---------------------------------------------------------------------------
__global__ __launch_bounds__(256) void k_attn(
    const short* __restrict__ qg, const short* __restrict__ kg,
    const short* __restrict__ vgT, const int* __restrict__ gs,
    const int* __restrict__ gep, const int* __restrict__ st_e,
    const int* __restrict__ st_row, const int* __restrict__ nstp,
    const int* __restrict__ perm, const short* __restrict__ WbT,
    const float* __restrict__ x, const float* __restrict__ bfv,
    const float* __restrict__ gamma, const float* __restrict__ beta,
    float* __restrict__ Op, float* __restrict__ lp, int* __restrict__ cnt,
    float* __restrict__ out) {
  int b = blockIdx.x;
  if (b >= *nstp) return;
  int h = blockIdx.y;
  int sp = blockIdx.z;
  int e = st_e[b];
  int row0 = st_row[b];
  int g0 = gs[e], kend = gep[e];
  int ntiles = (kend - g0 + 63) >> 6;
  int tpc = (ntiles + NSPLIT - 1) / NSPLIT;
  int t0i = sp * tpc;
  int t1i = min(ntiles, t0i + tpc);
  int start = g0 + t0i * 64, end = g0 + t1i * 64;

  int tid = threadIdx.x;
  int wl = tid >> 6, lane = tid & 63;
  int m = lane & 15, quad = lane >> 4;
  int r0 = tid >> 3;
  int c0 = (tid & 7) * 8;

  __shared__ union {
    struct { short k[64 * 72]; short v[64 * 72]; short p[4 * 16 * 72]; } at;
    float h[16 * 260];  // combiner LN staging (re-used after full sync)
  } smu;
  __shared__ int lastf;

  short* k_s = smu.at.k;
  short* v_s = smu.at.v;
  short* p_s = smu.at.p;

  f4 o_acc[4];
  float l_r[4];
#pragma unroll
  for (int t = 0; t < 4; t++) o_acc[t] = (f4){0.f, 0.f, 0.f, 0.f};
#pragma unroll
  for (int r = 0; r < 4; r++) l_r[r] = 0.f;

  if (start < end) {
    int qrow = row0 + wl * 16 + m;
    if (qrow >= kend) qrow = row0;
    s8 qf0 = *(const s8*)&qg[(size_t)qrow * DIM + h * DPH + quad * 8];
    s8 qf1 = *(const s8*)&qg[(size_t)qrow * DIM + h * DPH + 32 + quad * 8];

    s8 pk0, pk1, pv0, pv1;
#define PREF(JT)                                                              \
  do {                                                                        \
    pk0 = *(const s8*)&kg[(size_t)((JT) + r0) * DIM + h * DPH + c0];          \
    pk1 = *(const s8*)&kg[(size_t)((JT) + r0 + 32) * DIM + h * DPH + c0];     \
    pv0 = *(const s8*)&vgT[(size_t)(h * DPH + r0) * VPITCH + (JT) + c0];      \
    pv1 = *(const s8*)&vgT[(size_t)(h * DPH + r0 + 32) * VPITCH + (JT) + c0]; \
  } while (0)

    PREF(start);
    for (int jt = start; jt < end; jt += 64) {
      __syncthreads();  // prev tile's LDS readers done
      *(s8*)&k_s[r0 * 72 + c0] = pk0;
      *(s8*)&k_s[(r0 + 32) * 72 + c0] = pk1;
      *(s8*)&v_s[r0 * 72 + c0] = pv0;
      *(s8*)&v_s[(r0 + 32) * 72 + c0] = pv1;
      int jn = jt + 64;
      if (jn < end) PREF(jn);  // overlap next tile's loads with compute
      __syncthreads();

      f4 s_acc[4];
#pragma unroll
      for (int t = 0; t < 4; t++) s_acc[t] = (f4){0.f, 0.f, 0.f, 0.f};
#pragma unroll
      for (int t = 0; t < 4; t++) {
        s8 kb0 = *(s8*)&k_s[(t * 16 + m) * 72 + quad * 8];
        s8 kb1 = *(s8*)&k_s[(t * 16 + m) * 72 + 32 + quad * 8];
        s_acc[t] = __builtin_amdgcn_mfma_f32_16x16x32_bf16(qf0, kb0, s_acc[t], 0, 0, 0);
        s_acc[t] = __builtin_amdgcn_mfma_f32_16x16x32_bf16(qf1, kb1, s_acc[t], 0, 0, 0);
      }

      // p = exp(s*scale) (bounded scores -> shift-free exact), tail-masked.
#pragma unroll
      for (int t = 0; t < 4; t++) {
        bool ok = (jt + t * 16 + m) < kend;
        float pv[4];
#pragma unroll
        for (int r = 0; r < 4; r++) {
          float p = ok ? exp2_hw(s_acc[t][r] * EXP2SCALE) : 0.f;
          l_r[r] += p;
          pv[r] = p;
        }
        unsigned p01 = cvt_pk_bf16(pv[0], pv[1]);
        unsigned p23 = cvt_pk_bf16(pv[2], pv[3]);
        int base = wl * 16 + quad * 4;
        int col = t * 16 + m;
        p_s[(base + 0) * 72 + col] = (short)p01;
        p_s[(base + 1) * 72 + col] = (short)(p01 >> 16);
        p_s[(base + 2) * 72 + col] = (short)p23;
        p_s[(base + 3) * 72 + col] = (short)(p23 >> 16);
      }

#pragma unroll
      for (int kk = 0; kk < 2; kk++) {
        s8 pa = *(s8*)&p_s[(wl * 16 + m) * 72 + kk * 32 + quad * 8];
#pragma unroll
        for (int t = 0; t < 4; t++) {
          s8 vb = *(s8*)&v_s[(t * 16 + m) * 72 + kk * 32 + quad * 8];
          o_acc[t] = __builtin_amdgcn_mfma_f32_16x16x32_bf16(pa, vb, o_acc[t], 0, 0, 0);
        }
      }
    }
#undef PREF
  }

  // Epilogue: agent-scope (sc1) partial stores -> visible at MALL without
  // any wbl2. Empty chunks write zeros so the combiner never reads poison.
  float* Ob = Op + (size_t)sp * GPAD * DIM;
#pragma unroll
  for (int r = 0; r < 4; r++) {
    float lt = l_r[r];
#pragma unroll
    for (int o = 8; o > 0; o >>= 1) lt += __shfl_xor(lt, o, 64);
    int grow = row0 + wl * 16 + quad * 4 + r;
    if (m == 0) store_agent(&lp[(size_t)(sp * NHEAD + h) * GPAD + grow], lt);
#pragma unroll
    for (int t = 0; t < 4; t++)
      store_agent(&Ob[(size_t)grow * DIM + h * DPH + t * 16 + m], o_acc[t][r]);
  }

  // Signal: __syncthreads drains vmcnt per wave (stores at MALL), then one
  // relaxed agent RMW. 8th finisher combines.
  __syncthreads();
  if (tid == 0) {
    unsigned old = __hip_atomic_fetch_add((unsigned*)&cnt[b], 1u,
                                          __ATOMIC_RELAXED,
                                          __HIP_MEMORY_SCOPE_AGENT);
    lastf = (old == (unsigned)(NHEAD * NSPLIT - 1));
  }
  __syncthreads();
  if (!lastf) return;

  // ---- last finisher: combine splits + out-proj + LayerNorm (64 rows) ----
  __builtin_amdgcn_fence(__ATOMIC_ACQUIRE, "agent");  // inv: see peers' data
  const short* Bp =
      WbT + (size_t)27 * 65536 + (size_t)(wl * 64 + m) * 256 + quad * 8;
  for (int sub = 0; sub < 4; sub++) {
    int gbase = row0 + sub * 16;
    int growm = gbase + m;
    // Padding rows (growm >= kend): lp=0 -> inv=inf -> NaN A-rows; their C
    // rows are computed but never stored (masked below).
    float inv_[NHEAD];
#pragma unroll
    for (int h2 = 0; h2 < NHEAD; h2++) {
      float s = 0.f;
#pragma unroll
      for (int s2 = 0; s2 < NSPLIT; s2++)
        s += lp[(size_t)(s2 * NHEAD + h2) * GPAD + growm];
      inv_[h2] = 1.f / s;
    }
    s8 af[8];
#pragma unroll
    for (int kc = 0; kc < 8; kc++) {
      f4 s0 = (f4){0.f, 0.f, 0.f, 0.f}, s1 = (f4){0.f, 0.f, 0.f, 0.f};
#pragma unroll
      for (int s2 = 0; s2 < NSPLIT; s2++) {
        const float* pp =
            Op + ((size_t)s2 * GPAD + growm) * DIM + kc * 32 + quad * 8;
        s0 += *(const f4*)pp;
        s1 += *(const f4*)(pp + 4);
      }
      float iv = inv_[kc >> 1];
      union { s8 v; unsigned u[4]; } a;
      a.u[0] = cvt_pk_bf16(s0[0] * iv, s0[1] * iv);
      a.u[1] = cvt_pk_bf16(s0[2] * iv, s0[3] * iv);
      a.u[2] = cvt_pk_bf16(s1[0] * iv, s1[1] * iv);
      a.u[3] = cvt_pk_bf16(s1[2] * iv, s1[3] * iv);
      af[kc] = a.v;
    }

    f4 acc2[4];
#pragma unroll
    for (int t = 0; t < 4; t++) acc2[t] = (f4){0.f, 0.f, 0.f, 0.f};
#pragma unroll
    for (int kc = 0; kc < 8; kc++)
#pragma unroll
      for (int t = 0; t < 4; t++) {
        s8 wb = *(const s8*)(Bp + t * 16 * 256 + kc * 32);
        acc2[t] = __builtin_amdgcn_mfma_f32_16x16x32_bf16(af[kc], wb, acc2[t], 0, 0, 0);
      }

    __syncthreads();  // arena handoff (attn bufs / prev chunk's h reads done)
    float* h_s = smu.h;
#pragma unroll
    for (int t = 0; t < 4; t++) {
      int col = wl * 64 + t * 16 + m;
      float bs = bfv[col];
#pragma unroll
      for (int r = 0; r < 4; r++)
        h_s[(quad * 4 + r) * 260 + col] = acc2[t][r] + bs;
    }
    __syncthreads();

#pragma unroll
    for (int rr = 0; rr < 4; rr++) {
      int row = wl * 4 + rr;
      int grow2 = gbase + row;
      bool v2 = grow2 < kend;
      int tok2 = perm[v2 ? grow2 : row0];
      float hv[4];
#pragma unroll
      for (int k2 = 0; k2 < 4; k2++)
        hv[k2] = h_s[row * 260 + lane + 64 * k2] +
                 x[(size_t)tok2 * DIM + lane + 64 * k2];
      float mean = wave_sum(hv[0] + hv[1] + hv[2] + hv[3]) * (1.f / 256.f);
      float sq = 0.f;
#pragma unroll
      for (int k2 = 0; k2 < 4; k2++) {
        float dd = hv[k2] - mean;
        sq += dd * dd;
      }
      float rstd = rsqrtf(wave_sum(sq) * (1.f / 256.f) + 1e-5f);
      if (v2) {
#pragma unroll
        for (int k2 = 0; k2 < 4; k2++) {
          int c = lane + 64 * k2;
          out[(size_t)tok2 * DIM + c] =
              gamma[c] * ((hv[k2] - mean) * rstd) + beta[c];
        }
      }
    }
  }
}

// ---------------------------------------------------------------------------
extern "C" void kernel_launch(void* const* d_in, const int* in_sizes, int n_in,
                              void* d_out, int out_size, void* d_ws,
                              size_t ws_size, hipStream_t stream) {
  const float* x = (const float*)d_in[0];
  const int* label = (const int*)d_in[1];
  const float* Wq = (const float*)d_in[2];
  const float* bq = (const float*)d_in[3];
  const float* Wk = (const float*)d_in[4];
  const float* bk = (const float*)d_in[5];
  const float* Wv = (const float*)d_in[6];
  const float* bv = (const float*)d_in[7];
  const float* Wf = (const float*)d_in[8];
  const float* bfv = (const float*)d_in[9];
  const float* gamma = (const float*)d_in[10];
  const float* beta = (const float*)d_in[11];
  float* out = (float*)d_out;

  // Workspace (~25 MB of 256 MB).
  int* perm = (int*)d_ws;        // 4800 slot
  int* iperm = perm + 4800;      // 4096
  int* gs = iperm + 4096;        // 16
  int* gep = gs + 16;            // 16
  int* st_e = gep + 16;          // 128
  int* st_row = st_e + 128;      // 128
  int* nstp = st_row + 128;      // 8
  int* cnt = nstp + 8;           // 88 (per-supertile finish counters)
  short* qg = (short*)((char*)d_ws + 65536);
  short* kg = qg + (size_t)GPAD * DIM;
  short* vgT = kg + (size_t)GPAD * DIM;
  short* WbT = vgT + (size_t)DIM * VPITCH;
  short* xb = WbT + (size_t)28 * 65536;
  float* Op = (float*)(xb + (size_t)N_TOK * DIM);   // [NSPLIT][GPAD][256] f32
  float* lp = Op + (size_t)NSPLIT * GPAD * DIM;     // [NSPLIT][4][GPAD] f32

  hipLaunchKernelGGL(k_prep, dim3(513), dim3(256), 0, stream, x, label, Wq, Wk,
                     Wv, Wf, perm, iperm, gs, gep, st_e, st_row, nstp, cnt,
                     WbT, xb);
  hipLaunchKernelGGL(k_proj, dim3(MAXST, 4, 3), dim3(256), 0, stream, xb, WbT,
                     bq, bk, bv, perm, gep, st_e, st_row, nstp, qg, kg, vgT);
  hipLaunchKernelGGL(k_attn, dim3(MAXST, NHEAD, NSPLIT), dim3(256), 0, stream,
                     qg, kg, vgT, gs, gep, st_e, st_row, nstp, perm, WbT, x,
                     bfv, gamma, beta, Op, lp, cnt, out);
}

// Round 8
// 138.107 us; speedup vs baseline: 1.4731x; 1.4731x over previous
//
#include <hip/hip_runtime.h>
#include <math.h>

#define N_TOK 4096
#define DIM 256
#define NHEAD 4
#define DPH 64
#define NEXP 9
#define SCALE 0.25f
#define MAXST 80    // 64-row supertiles: <= 64 + 9
#define GPAD 4736   // 64-aligned grouped rows upper bound
#define VPITCH 4736
#define NSPLIT 2    // key-range splits per (supertile, head)
// exp(x*SCALE) = 2^(x * SCALE*log2(e))
#define EXP2SCALE 0.36067376022224085f

typedef short s8 __attribute__((ext_vector_type(8)));
typedef short s4 __attribute__((ext_vector_type(4)));
typedef float f4 __attribute__((ext_vector_type(4)));

// HW packed f32->bf16 (RNE), 1 VALU op for 2 values (no builtin on gfx950).
static __device__ __forceinline__ unsigned cvt_pk_bf16(float a, float b) {
  unsigned r;
  asm("v_cvt_pk_bf16_f32 %0, %1, %2" : "=v"(r) : "v"(a), "v"(b));
  return r;
}

static __device__ __forceinline__ float exp2_hw(float x) {
  float r;
  asm("v_exp_f32 %0, %1" : "=v"(r) : "v"(x));
  return r;
}

static __device__ __forceinline__ float wave_sum(float v) {
#pragma unroll
  for (int o = 32; o > 0; o >>= 1) v += __shfl_xor(v, o, 64);
  return v;
}

// ---------------------------------------------------------------------------
// Kernel 1: prep. Block 0: bucket tokens — ATOMIC-FREE build: per-wave ballot
// histogram, LDS cross-wave prefix, deterministic rank scatter. Blocks
// 1..448: W fp32 [d][h] -> WbT bf16 [slab][h][d]. Blocks 449..512: x -> bf16.
// ---------------------------------------------------------------------------
__global__ __launch_bounds__(256) void k_prep(
    const float* __restrict__ x, const int* __restrict__ label,
    const float* __restrict__ Wq, const float* __restrict__ Wk,
    const float* __restrict__ Wv, const float* __restrict__ Wf,
    int* __restrict__ perm, int* __restrict__ iperm, int* __restrict__ gs,
    int* __restrict__ gep, int* __restrict__ st_e, int* __restrict__ st_row,
    int* __restrict__ nstp, short* __restrict__ WbT, short* __restrict__ xb) {
  int b = blockIdx.x;
  int tid = threadIdx.x;
  if (b == 0) {
    __shared__ int cnt_s[4][NEXP];  // per-wave counts
    __shared__ int gsh[NEXP];       // group starts (LDS copy)
    int wl = tid >> 6, lane = tid & 63;
    int lab[16];
#pragma unroll
    for (int i = 0; i < 16; i++) lab[i] = label[wl * 1024 + i * 64 + lane];

    int cw[NEXP];
#pragma unroll
    for (int e = 0; e < NEXP; e++) cw[e] = 0;
#pragma unroll
    for (int i = 0; i < 16; i++)
#pragma unroll
      for (int e = 0; e < NEXP; e++)
        cw[e] += __popcll(__ballot(lab[i] == e));
    if (lane == 0)
#pragma unroll
      for (int e = 0; e < NEXP; e++) cnt_s[wl][e] = cw[e];
    __syncthreads();

    if (tid == 0) {
      int run = 0, ns = 0;
      for (int e = 0; e < NEXP; e++) {
        int tot = cnt_s[0][e] + cnt_s[1][e] + cnt_s[2][e] + cnt_s[3][e];
        gs[e] = run;
        gsh[e] = run;
        int end = run + tot;
        gep[e] = end;
        for (int r = run; r < end; r += 64) {
          st_e[ns] = e;
          st_row[ns] = r;
          ns++;
        }
        run = (end + 63) & ~63;  // 64-align next group start
      }
      *nstp = ns;
    }
    __syncthreads();

    int baseW[NEXP];
#pragma unroll
    for (int e = 0; e < NEXP; e++) {
      int bse = gsh[e];
      for (int w = 0; w < 4; w++)
        if (w < wl) bse += cnt_s[w][e];
      baseW[e] = bse;
    }
    int run2[NEXP];
#pragma unroll
    for (int e = 0; e < NEXP; e++) run2[e] = 0;
#pragma unroll
    for (int i = 0; i < 16; i++) {
      int t = wl * 1024 + i * 64 + lane;
      int lv = lab[i];
      unsigned long long below = (1ull << lane) - 1ull;
      int pos = 0;
#pragma unroll
      for (int e = 0; e < NEXP; e++) {
        unsigned long long mk = __ballot(lv == e);
        if (lv == e) pos = baseW[e] + run2[e] + __popcll(mk & below);
        run2[e] += __popcll(mk);
      }
      perm[pos] = t;
      iperm[t] = pos;
    }
  } else if (b <= 448) {
    // Weight transpose: slabs 0-8 Wq, 9-17 Wk, 18-26 Wv, 27 Wf; 16 tiles/slab.
    __shared__ short tile[64 * 68];
    int vt = b - 1;
    int slab = vt >> 4;
    const float* src = (slab < 9)    ? Wq + (size_t)slab * 65536
                       : (slab < 18) ? Wk + (size_t)(slab - 9) * 65536
                       : (slab < 27) ? Wv + (size_t)(slab - 18) * 65536
                                     : Wf;
    int xy = vt & 15;
    int d0 = (xy >> 2) * 64, h0 = (xy & 3) * 64;
    int rl = tid >> 4;
    int hh = (tid & 15) * 4;
#pragma unroll
    for (int p = 0; p < 4; p++) {
      int dl = p * 16 + rl;
      float4 v = *(const float4*)(src + (size_t)(d0 + dl) * 256 + h0 + hh);
      union { s4 v; unsigned u[2]; } o;
      o.u[0] = cvt_pk_bf16(v.x, v.y);
      o.u[1] = cvt_pk_bf16(v.z, v.w);
      *(s4*)&tile[dl * 68 + hh] = o.v;
    }
    __syncthreads();
    int h = tid >> 2, dq = (tid & 3) * 16;
    s8 pa, pb;
#pragma unroll
    for (int i = 0; i < 8; i++) {
      pa[i] = tile[(dq + i) * 68 + h];
      pb[i] = tile[(dq + 8 + i) * 68 + h];
    }
    short* dst = WbT + (size_t)slab * 65536 + (size_t)(h0 + h) * 256 + d0 + dq;
    *(s8*)dst = pa;
    *(s8*)(dst + 8) = pb;
  } else {
    // x -> bf16, token order.
    int tok = (b - 449) * 64 + (tid >> 2);
    int qd = (tid & 3) * 64;
    const float* src = x + (size_t)tok * DIM + qd;
    short* dst = xb + (size_t)tok * DIM + qd;
#pragma unroll
    for (int i = 0; i < 16; i++) {
      float4 v = *(const float4*)(src + i * 4);
      union { s4 v; unsigned u[2]; } o;
      o.u[0] = cvt_pk_bf16(v.x, v.y);
      o.u[1] = cvt_pk_bf16(v.z, v.w);
      *(s4*)(dst + i * 4) = o.v;
    }
  }
}

// ---------------------------------------------------------------------------
// Kernel 2: MFMA QKV projection. Grid (supertile, colblock 0..3, mtx 0..2);
// wave = 16 grouped rows x 64 cols; A-frags gathered via perm (clamped).
// ---------------------------------------------------------------------------
__global__ __launch_bounds__(256) void k_proj(
    const short* __restrict__ xb, const short* __restrict__ WbT,
    const float* __restrict__ bq, const float* __restrict__ bk,
    const float* __restrict__ bv, const int* __restrict__ perm,
    const int* __restrict__ gep, const int* __restrict__ st_e,
    const int* __restrict__ st_row, const int* __restrict__ nstp,
    short* __restrict__ qg, short* __restrict__ kg, short* __restrict__ vgT) {
  int b = blockIdx.x;
  if (b >= *nstp) return;
  int gy = blockIdx.y;
  int mtx = blockIdx.z;
  int e = st_e[b];
  int row0 = st_row[b];
  int g1 = gep[e];
  int tid = threadIdx.x, wl = tid >> 6, lane = tid & 63;
  int m = lane & 15, quad = lane >> 4;

  __shared__ short st_s[4][16 * 72];  // per-wave store-transpose buffer

  int row = row0 + wl * 16 + m;
  int pr = perm[(row < g1) ? row : row0];  // clamp padding rows
  const short* Ap = xb + (size_t)pr * DIM + quad * 8;
  const short* Bp = WbT + (size_t)(mtx * 9 + e) * 65536 +
                    (size_t)(gy * 64 + m) * 256 + quad * 8;
  const float* bias = (mtx == 0) ? bq : (mtx == 1) ? bk : bv;

  s8 ac = *(const s8*)Ap;
  s8 bc[4];
#pragma unroll
  for (int t = 0; t < 4; t++) bc[t] = *(const s8*)(Bp + t * 16 * 256);
  f4 acc[4];
#pragma unroll
  for (int t = 0; t < 4; t++) acc[t] = (f4){0.f, 0.f, 0.f, 0.f};
#pragma unroll
  for (int kc = 0; kc < 8; kc++) {
    s8 an = ac;
    s8 bn[4] = {bc[0], bc[1], bc[2], bc[3]};
    if (kc < 7) {
      an = *(const s8*)(Ap + (kc + 1) * 32);
#pragma unroll
      for (int t = 0; t < 4; t++)
        bn[t] = *(const s8*)(Bp + t * 16 * 256 + (kc + 1) * 32);
    }
#pragma unroll
    for (int t = 0; t < 4; t++)
      acc[t] = __builtin_amdgcn_mfma_f32_16x16x32_bf16(ac, bc[t], acc[t], 0, 0, 0);
    ac = an;
#pragma unroll
    for (int t = 0; t < 4; t++) bc[t] = bn[t];
  }

  if (mtx == 2) {
    // vgT[col][grow]: quad owns 4 consecutive grows per col -> 8B s4 stores.
#pragma unroll
    for (int t = 0; t < 4; t++) {
      int col = gy * 64 + t * 16 + m;
      float bs = bias[e * DIM + col];
      union { s4 v; unsigned u[2]; } o;
      o.u[0] = cvt_pk_bf16(acc[t][0] + bs, acc[t][1] + bs);
      o.u[1] = cvt_pk_bf16(acc[t][2] + bs, acc[t][3] + bs);
      *(s4*)&vgT[(size_t)col * VPITCH + row0 + wl * 16 + quad * 4] = o.v;
    }
  } else {
    // LDS transpose: C-layout -> [row][col] bf16, then coalesced stores.
    short* ws = st_s[wl];
#pragma unroll
    for (int t = 0; t < 4; t++) {
      int col = gy * 64 + t * 16 + m;
      float bs = bias[e * DIM + col];
      unsigned p01 = cvt_pk_bf16(acc[t][0] + bs, acc[t][1] + bs);
      unsigned p23 = cvt_pk_bf16(acc[t][2] + bs, acc[t][3] + bs);
      int base = quad * 4;
      ws[(base + 0) * 72 + t * 16 + m] = (short)p01;
      ws[(base + 1) * 72 + t * 16 + m] = (short)(p01 >> 16);
      ws[(base + 2) * 72 + t * 16 + m] = (short)p23;
      ws[(base + 3) * 72 + t * 16 + m] = (short)(p23 >> 16);
    }
    // same-wave LDS ordering (compiler inserts lgkmcnt)
    int rr = lane >> 2, cg2 = (lane & 3) * 16;
    s8 v0 = *(s8*)&ws[rr * 72 + cg2];
    s8 v1 = *(s8*)&ws[rr * 72 + cg2 + 8];
    short* dst = ((mtx == 1) ? kg : qg) +
                 (size_t)(row0 + wl * 16 + rr) * DIM + gy * 64 + cg2;
    *(s8*)dst = v0;
    *(s8*)(dst + 8) = v1;
  }
}

// ---------------------------------------------------------------------------
// Kernel 3: split-K MFMA flash attention (single-buffered K/V staging).
// Fixed-shift softmax -> additive partials; k_out combines. Softmax VALU
// diet: premultiplied v_exp_f32 and v_cvt_pk_bf16_f32 pairs.
// ---------------------------------------------------------------------------
__global__ __launch_bounds__(256) void k_attn(
    const short* __restrict__ qg, const short* __restrict__ kg,
    const short* __restrict__ vgT, const int* __restrict__ gs,
    const int* __restrict__ gep, const int* __restrict__ st_e,
    const int* __restrict__ st_row, const int* __restrict__ nstp,
    float* __restrict__ Op, float* __restrict__ lp) {
  int b = blockIdx.x;
  if (b >= *nstp) return;
  int h = blockIdx.y;
  int sp = blockIdx.z;
  int e = st_e[b];
  int row0 = st_row[b];
  int g0 = gs[e], kend = gep[e];
  int ntiles = (kend - g0 + 63) >> 6;
  int tpc = (ntiles + NSPLIT - 1) / NSPLIT;
  int t0i = sp * tpc;
  int t1i = min(ntiles, t0i + tpc);
  int start = g0 + t0i * 64, end = g0 + t1i * 64;

  int tid = threadIdx.x;
  int wl = tid >> 6, lane = tid & 63;
  int m = lane & 15, quad = lane >> 4;
  int r0 = tid >> 3;
  int c0 = (tid & 7) * 8;

  __shared__ short k_s[64 * 72];      // [key][dph]
  __shared__ short v_s[64 * 72];      // [dph][key] (transposed)
  __shared__ short p_s[4 * 16 * 72];  // per-wave [qrow][key]

  f4 o_acc[4];
  float l_r[4];
#pragma unroll
  for (int t = 0; t < 4; t++) o_acc[t] = (f4){0.f, 0.f, 0.f, 0.f};
#pragma unroll
  for (int r = 0; r < 4; r++) l_r[r] = 0.f;

  if (start < end) {
    int qrow = row0 + wl * 16 + m;
    if (qrow >= kend) qrow = row0;
    s8 qf0 = *(const s8*)&qg[(size_t)qrow * DIM + h * DPH + quad * 8];
    s8 qf1 = *(const s8*)&qg[(size_t)qrow * DIM + h * DPH + 32 + quad * 8];

    s8 pk0, pk1, pv0, pv1;
#define PREF(JT)                                                              \
  do {                                                                        \
    pk0 = *(const s8*)&kg[(size_t)((JT) + r0) * DIM + h * DPH + c0];          \
    pk1 = *(const s8*)&kg[(size_t)((JT) + r0 + 32) * DIM + h * DPH + c0];     \
    pv0 = *(const s8*)&vgT[(size_t)(h * DPH + r0) * VPITCH + (JT) + c0];      \
    pv1 = *(const s8*)&vgT[(size_t)(h * DPH + r0 + 32) * VPITCH + (JT) + c0]; \
  } while (0)

    PREF(start);
    for (int jt = start; jt < end; jt += 64) {
      __syncthreads();  // prev tile's LDS readers done
      *(s8*)&k_s[r0 * 72 + c0] = pk0;
      *(s8*)&k_s[(r0 + 32) * 72 + c0] = pk1;
      *(s8*)&v_s[r0 * 72 + c0] = pv0;
      *(s8*)&v_s[(r0 + 32) * 72 + c0] = pv1;
      int jn = jt + 64;
      if (jn < end) PREF(jn);  // overlap next tile's loads with compute
      __syncthreads();

      f4 s_acc[4];
#pragma unroll
      for (int t = 0; t < 4; t++) s_acc[t] = (f4){0.f, 0.f, 0.f, 0.f};
#pragma unroll
      for (int t = 0; t < 4; t++) {
        s8 kb0 = *(s8*)&k_s[(t * 16 + m) * 72 + quad * 8];
        s8 kb1 = *(s8*)&k_s[(t * 16 + m) * 72 + 32 + quad * 8];
        s_acc[t] = __builtin_amdgcn_mfma_f32_16x16x32_bf16(qf0, kb0, s_acc[t], 0, 0, 0);
        s_acc[t] = __builtin_amdgcn_mfma_f32_16x16x32_bf16(qf1, kb1, s_acc[t], 0, 0, 0);
      }

      // p = exp(s*scale) (bounded scores -> shift-free exact), tail-masked.
#pragma unroll
      for (int t = 0; t < 4; t++) {
        bool ok = (jt + t * 16 + m) < kend;
        float pv[4];
#pragma unroll
        for (int r = 0; r < 4; r++) {
          float p = ok ? exp2_hw(s_acc[t][r] * EXP2SCALE) : 0.f;
          l_r[r] += p;
          pv[r] = p;
        }
        unsigned p01 = cvt_pk_bf16(pv[0], pv[1]);
        unsigned p23 = cvt_pk_bf16(pv[2], pv[3]);
        int base = wl * 16 + quad * 4;
        int col = t * 16 + m;
        p_s[(base + 0) * 72 + col] = (short)p01;
        p_s[(base + 1) * 72 + col] = (short)(p01 >> 16);
        p_s[(base + 2) * 72 + col] = (short)p23;
        p_s[(base + 3) * 72 + col] = (short)(p23 >> 16);
      }

#pragma unroll
      for (int kk = 0; kk < 2; kk++) {
        s8 pa = *(s8*)&p_s[(wl * 16 + m) * 72 + kk * 32 + quad * 8];
#pragma unroll
        for (int t = 0; t < 4; t++) {
          s8 vb = *(s8*)&v_s[(t * 16 + m) * 72 + kk * 32 + quad * 8];
          o_acc[t] = __builtin_amdgcn_mfma_f32_16x16x32_bf16(pa, vb, o_acc[t], 0, 0, 0);
        }
      }
    }
#undef PREF
  }

  // Epilogue: write UNNORMALIZED partial O (f32, coalesced 64B segments) +
  // partial l. Empty chunks write zeros so k_out never reads poisoned ws.
  float* Ob = Op + (size_t)sp * GPAD * DIM;
#pragma unroll
  for (int r = 0; r < 4; r++) {
    float lt = l_r[r];
#pragma unroll
    for (int o = 8; o > 0; o >>= 1) lt += __shfl_xor(lt, o, 64);
    int grow = row0 + wl * 16 + quad * 4 + r;
    if (m == 0) lp[(size_t)(sp * NHEAD + h) * GPAD + grow] = lt;
#pragma unroll
    for (int t = 0; t < 4; t++)
      Ob[(size_t)grow * DIM + h * DPH + t * 16 + m] = o_acc[t][r];
  }
}

// ---------------------------------------------------------------------------
// Kernel 4: combine splits + out-proj + LayerNorm. Block = 16 tokens (token
// order). Each thread sums NSPLIT partials for its A-frag row, divides by
// summed l, converts to bf16 frags via cvt_pk, then MFMA Wf GEMM +
// residual + LN.
// ---------------------------------------------------------------------------
__global__ __launch_bounds__(256) void k_out(
    const float* __restrict__ Op, const float* __restrict__ lp,
    const int* __restrict__ iperm, const short* __restrict__ WbT,
    const float* __restrict__ x, const float* __restrict__ bfv,
    const float* __restrict__ gamma, const float* __restrict__ beta,
    float* __restrict__ out) {
  int t0 = blockIdx.x * 16;
  int tid = threadIdx.x, wl = tid >> 6, lane = tid & 63;
  int m = lane & 15, quad = lane >> 4;
  __shared__ float h_s[16 * 260];

  int grow = iperm[t0 + m];
  float inv[NHEAD];
#pragma unroll
  for (int h = 0; h < NHEAD; h++) {
    float s = 0.f;
#pragma unroll
    for (int sp = 0; sp < NSPLIT; sp++)
      s += lp[(size_t)(sp * NHEAD + h) * GPAD + grow];
    inv[h] = 1.f / s;
  }

  s8 af[8];
#pragma unroll
  for (int kc = 0; kc < 8; kc++) {
    f4 s0 = (f4){0.f, 0.f, 0.f, 0.f}, s1 = (f4){0.f, 0.f, 0.f, 0.f};
#pragma unroll
    for (int sp = 0; sp < NSPLIT; sp++) {
      const float* p =
          Op + ((size_t)sp * GPAD + grow) * DIM + kc * 32 + quad * 8;
      s0 += *(const f4*)p;
      s1 += *(const f4*)(p + 4);
    }
    float iv = inv[kc >> 1];
    union { s8 v; unsigned u[4]; } a;
    a.u[0] = cvt_pk_bf16(s0[0] * iv, s0[1] * iv);
    a.u[1] = cvt_pk_bf16(s0[2] * iv, s0[3] * iv);
    a.u[2] = cvt_pk_bf16(s1[0] * iv, s1[1] * iv);
    a.u[3] = cvt_pk_bf16(s1[2] * iv, s1[3] * iv);
    af[kc] = a.v;
  }

  const short* Bp =
      WbT + (size_t)27 * 65536 + (size_t)(wl * 64 + m) * 256 + quad * 8;
  f4 acc[4];
#pragma unroll
  for (int t = 0; t < 4; t++) acc[t] = (f4){0.f, 0.f, 0.f, 0.f};
#pragma unroll
  for (int kc = 0; kc < 8; kc++)
#pragma unroll
    for (int t = 0; t < 4; t++) {
      s8 wb = *(const s8*)(Bp + t * 16 * 256 + kc * 32);
      acc[t] = __builtin_amdgcn_mfma_f32_16x16x32_bf16(af[kc], wb, acc[t], 0, 0, 0);
    }

#pragma unroll
  for (int t = 0; t < 4; t++) {
    int col = wl * 64 + t * 16 + m;
    float bs = bfv[col];
#pragma unroll
    for (int r = 0; r < 4; r++) h_s[(quad * 4 + r) * 260 + col] = acc[t][r] + bs;
  }
  __syncthreads();

#pragma unroll
  for (int rr = 0; rr < 4; rr++) {
    int row = wl * 4 + rr;
    float hv[4];
#pragma unroll
    for (int k2 = 0; k2 < 4; k2++)
      hv[k2] = h_s[row * 260 + lane + 64 * k2] +
               x[(size_t)(t0 + row) * DIM + lane + 64 * k2];
    float mean = wave_sum(hv[0] + hv[1] + hv[2] + hv[3]) * (1.f / 256.f);
    float sq = 0.f;
#pragma unroll
    for (int k2 = 0; k2 < 4; k2++) {
      float dd = hv[k2] - mean;
      sq += dd * dd;
    }
    float rstd = rsqrtf(wave_sum(sq) * (1.f / 256.f) + 1e-5f);
#pragma unroll
    for (int k2 = 0; k2 < 4; k2++) {
      int c = lane + 64 * k2;
      out[(size_t)(t0 + row) * DIM + c] =
          gamma[c] * ((hv[k2] - mean) * rstd) + beta[c];
    }
  }
}

// ---------------------------------------------------------------------------
extern "C" void kernel_launch(void* const* d_in, const int* in_sizes, int n_in,
                              void* d_out, int out_size, void* d_ws,
                              size_t ws_size, hipStream_t stream) {
  const float* x = (const float*)d_in[0];
  const int* label = (const int*)d_in[1];
  const float* Wq = (const float*)d_in[2];
  const float* bq = (const float*)d_in[3];
  const float* Wk = (const float*)d_in[4];
  const float* bk = (const float*)d_in[5];
  const float* Wv = (const float*)d_in[6];
  const float* bv = (const float*)d_in[7];
  const float* Wf = (const float*)d_in[8];
  const float* bfv = (const float*)d_in[9];
  const float* gamma = (const float*)d_in[10];
  const float* beta = (const float*)d_in[11];
  float* out = (float*)d_out;

  // Workspace (~25 MB of 256 MB).
  int* perm = (int*)d_ws;        // 4800 slot
  int* iperm = perm + 4800;      // 4096
  int* gs = iperm + 4096;        // 16
  int* gep = gs + 16;            // 16
  int* st_e = gep + 16;          // 128
  int* st_row = st_e + 128;      // 128
  int* nstp = st_row + 128;      // 8
  short* qg = (short*)((char*)d_ws + 65536);
  short* kg = qg + (size_t)GPAD * DIM;
  short* vgT = kg + (size_t)GPAD * DIM;
  short* WbT = vgT + (size_t)DIM * VPITCH;
  short* xb = WbT + (size_t)28 * 65536;
  float* Op = (float*)(xb + (size_t)N_TOK * DIM);   // [NSPLIT][GPAD][256] f32
  float* lp = Op + (size_t)NSPLIT * GPAD * DIM;     // [NSPLIT][4][GPAD] f32

  hipLaunchKernelGGL(k_prep, dim3(513), dim3(256), 0, stream, x, label, Wq, Wk,
                     Wv, Wf, perm, iperm, gs, gep, st_e, st_row, nstp, WbT, xb);
  hipLaunchKernelGGL(k_proj, dim3(MAXST, 4, 3), dim3(256), 0, stream, xb, WbT,
                     bq, bk, bv, perm, gep, st_e, st_row, nstp, qg, kg, vgT);
  hipLaunchKernelGGL(k_attn, dim3(MAXST, NHEAD, NSPLIT), dim3(256), 0, stream,
                     qg, kg, vgT, gs, gep, st_e, st_row, nstp, Op, lp);
  hipLaunchKernelGGL(k_out, dim3(N_TOK / 16), dim3(256), 0, stream, Op, lp,
                     iperm, WbT, x, bfv, gamma, beta, out);
}